// Round 6
// baseline (177.190 us; speedup 1.0000x reference)
//
#include <hip/hip_runtime.h>

// SWA non-overlapping window MHA, MI355X gfx950.
// B=8, S=4096, D=512, W=128, H=8, hd=64 -> 256 windows, M=32768 tokens.
// K1 convert fp32->bf16 (x, w_in, w_out)
// K2 QKV GEMM [32768x1536x512]: 256x256xBK64, 2-deep dbuf, 4 phases/tile,
//    4-phase-old vmcnt waits, through-LDS coalesced epilogue -> qk + vT
// K3 attention per (window, head), no barriers -> ctx bf16 [M][512]
// K4 out-proj GEMM [32768x512x512] + bias -> fp32 d_out (same template)

typedef __bf16 bf16x8 __attribute__((ext_vector_type(8)));
typedef float  f32x4  __attribute__((ext_vector_type(4)));

#define MFMA16(a, b, c) __builtin_amdgcn_mfma_f32_16x16x32_bf16((a), (b), (c), 0, 0, 0)

#define VMCNT_(n) asm volatile("s_waitcnt vmcnt(" #n ")" ::: "memory")
#define VMCNT(n) VMCNT_(n)
#define LGKM0() asm volatile("s_waitcnt lgkmcnt(0)" ::: "memory")

__device__ __forceinline__ void gload_lds16(const __bf16* g, void* l) {
    __builtin_amdgcn_global_load_lds(
        (const __attribute__((address_space(1))) unsigned int*)g,
        (__attribute__((address_space(3))) unsigned int*)l, 16, 0, 0);
}

// ---------------- K1: fp32 -> bf16 conversion ----------------
__device__ __forceinline__ void cvt8(const float* __restrict__ s,
                                     __bf16* __restrict__ d, long i) {
    const float4* s4 = reinterpret_cast<const float4*>(s);
    float4 a = s4[2 * i], b = s4[2 * i + 1];
    bf16x8 v;
    v[0] = (__bf16)a.x; v[1] = (__bf16)a.y; v[2] = (__bf16)a.z; v[3] = (__bf16)a.w;
    v[4] = (__bf16)b.x; v[5] = (__bf16)b.y; v[6] = (__bf16)b.z; v[7] = (__bf16)b.w;
    *reinterpret_cast<bf16x8*>(d + 8 * i) = v;
}

__global__ void convert_k(const float* __restrict__ x,
                          const float* __restrict__ w_in,
                          const float* __restrict__ w_out,
                          __bf16* __restrict__ x_bf,
                          __bf16* __restrict__ w_in_bf,
                          __bf16* __restrict__ w_out_bf)
{
    long i0 = (long)blockIdx.x * blockDim.x + threadIdx.x;
    long stride = (long)gridDim.x * blockDim.x;
    for (long i = i0; i < 16777216 / 8; i += stride) cvt8(x, x_bf, i);
    for (long i = i0; i < 786432 / 8;   i += stride) cvt8(w_in, w_in_bf, i);
    for (long i = i0; i < 262144 / 8;   i += stride) cvt8(w_out, w_out_bf, i);
}

// ---------------- K2/K4: 256x256xBK64 GEMM, K=512 (8 tiles) ----------------
// LDS 128 KiB: A[2 bufs][256 rows][64 k] at 0, B same at +64 KiB.
// 8-slot XOR swizzle (slot ^= row&7) -> conflict-free ds_read_b128.
// Stage: 8 gload_lds per thread per tile, issued at tile p0; vmcnt at next
// tile's p0 waits only on 4-phase-old loads. One s_barrier per phase.
// Epilogue: acc -> swizzled LDS tile -> coalesced 16B global stores.
template<int EPI, int NN>
__global__ __launch_bounds__(512, 2)
void gemm256(const __bf16* __restrict__ A,
             const __bf16* __restrict__ Bw,
             const float* __restrict__ bias,
             void* __restrict__ Cq,
             __bf16* __restrict__ vT)
{
    __shared__ __align__(16) char smem[131072];

    const int nwg = gridDim.x;
    const int chunk = nwg >> 3;                       // nwg % 8 == 0
    const int bid = blockIdx.x;
    const int wg = (bid & 7) * chunk + (bid >> 3);    // XCD-contiguous chunks
    const int nidx = wg % NN;
    const int midx = wg / NN;
    const long mbase = (long)midx * 256;
    const int colbase = nidx * 256;

    const int tid = threadIdx.x;
    const int w = tid >> 6, lane = tid & 63;
    const int lrow = lane & 15, hi = lane >> 4;
    const int quad = lane >> 4, sl = lane & 15;
    const int wm = w >> 2, wn = w & 3;                // wave tile: rows 128*wm, cols 64*wn

    // staging: wave w covers 8-row chunks {w, 8+w, 16+w, 24+w} of the 256-row tile;
    // lane -> row = 8w + (lane>>3), 16B slot pre-swizzled: (lane&7) ^ (lane>>3)
    const int l8 = lane >> 3;
    const int slotp = (lane & 7) ^ l8;
    const __bf16* stA = A  + (mbase + 8 * w + l8) * 512 + slotp * 8;
    const __bf16* stB = Bw + ((long)colbase + 8 * w + l8) * 512 + slotp * 8;
    const int ldsw = w * 1024;

    auto stage8 = [&](int tt) {
        char* As = smem + (tt & 1) * 32768;
        char* Bs = smem + 65536 + (tt & 1) * 32768;
        const int ko = tt * 64;
        gload_lds16(stA + ko,             As + ldsw);
        gload_lds16(stA + 64 * 512 + ko,  As + 8192 + ldsw);
        gload_lds16(stA + 128 * 512 + ko, As + 16384 + ldsw);
        gload_lds16(stA + 192 * 512 + ko, As + 24576 + ldsw);
        gload_lds16(stB + ko,             Bs + ldsw);
        gload_lds16(stB + 64 * 512 + ko,  Bs + 8192 + ldsw);
        gload_lds16(stB + 128 * 512 + ko, Bs + 16384 + ldsw);
        gload_lds16(stB + 192 * 512 + ko, Bs + 24576 + ldsw);
    };

    f32x4 acc[8][4];
    #pragma unroll
    for (int rt = 0; rt < 8; ++rt)
        #pragma unroll
        for (int ct = 0; ct < 4; ++ct) acc[rt][ct] = (f32x4){0.f, 0.f, 0.f, 0.f};

    bf16x8 af[4], bfr[4];

    // Phase: 4 A-frags (rows RT0..RT0+3 of wave half) x 4 B-frags x 1 kk = 16 MFMA.
#define PHASE(T, KK, RT0, LB)                                                     \
    {                                                                             \
        const char* As = smem + ((T) & 1) * 32768;                                \
        const char* Bs = smem + 65536 + ((T) & 1) * 32768;                        \
        const int ko = ((KK) * 64 + hi * 16) ^ ((lrow & 7) << 4);                 \
        if (LB) {                                                                 \
            _Pragma("unroll")                                                     \
            for (int ct = 0; ct < 4; ++ct)                                        \
                bfr[ct] = *reinterpret_cast<const bf16x8*>(                       \
                    Bs + (64 * wn + 16 * ct + lrow) * 128 + ko);                  \
        }                                                                         \
        _Pragma("unroll")                                                         \
        for (int i = 0; i < 4; ++i)                                               \
            af[i] = *reinterpret_cast<const bf16x8*>(                             \
                As + (128 * wm + 16 * ((RT0) + i) + lrow) * 128 + ko);            \
        __builtin_amdgcn_s_setprio(1);                                            \
        _Pragma("unroll")                                                         \
        for (int i = 0; i < 4; ++i)                                               \
            _Pragma("unroll")                                                     \
            for (int ct = 0; ct < 4; ++ct)                                        \
                acc[(RT0) + i][ct] = MFMA16(af[i], bfr[ct], acc[(RT0) + i][ct]);  \
        __builtin_amdgcn_s_setprio(0);                                            \
    }

    // prologue: stage tiles 0 and 1 (16 loads/thread); wait tile 0 (8 left)
    stage8(0); stage8(1);
    VMCNT(8);
    __builtin_amdgcn_s_barrier();

    #pragma unroll 1
    for (int t = 0; t < 8; ++t) {
        if (t) {
            VMCNT(0);                      // waits only on tile-t loads, issued
            __builtin_amdgcn_s_barrier();  // 4 phases (~1200 cyc) earlier
            if (t < 7) stage8(t + 1);      // buf (t+1)&1 free: tile t-1 reads done
        }
        PHASE(t, 0, 0, 1);
        __builtin_amdgcn_s_barrier();
        PHASE(t, 0, 4, 0);
        __builtin_amdgcn_s_barrier();
        PHASE(t, 1, 0, 1);
        __builtin_amdgcn_s_barrier();
        PHASE(t, 1, 4, 0);
    }
#undef PHASE
    __builtin_amdgcn_s_barrier();          // all LDS reads done; smem reusable

    // ---- epilogue: acc -> swizzled LDS -> coalesced stores ----
    const int colg0 = colbase + 64 * wn + lrow;
    if (EPI == 0) {
        if (colbase < 1024) {
            // q/k: LDS [256 tok][256 col] bf16, slot ^= row&31
            const float scale = (colbase < 512) ? 0.125f : 1.0f;
            __bf16* qk = (__bf16*)Cq;
            #pragma unroll
            for (int ct = 0; ct < 4; ++ct) {
                float b = bias[colg0 + 16 * ct];
                int col2 = (64 * wn + 16 * ct + lrow) * 2;
                #pragma unroll
                for (int rt = 0; rt < 8; ++rt)
                    #pragma unroll
                    for (int r = 0; r < 4; ++r) {
                        int row = 128 * wm + 16 * rt + 4 * hi + r;
                        *reinterpret_cast<__bf16*>(
                            smem + row * 512 + (col2 ^ ((row & 31) << 4))) =
                            (__bf16)((acc[rt][ct][r] + b) * scale);
                    }
            }
            LGKM0();
            __builtin_amdgcn_s_barrier();
            #pragma unroll
            for (int i = 0; i < 8; ++i) {
                int row = 32 * w + 4 * i + quad;
                #pragma unroll
                for (int h2 = 0; h2 < 2; ++h2) {
                    int slot = (16 * h2 + sl) ^ (row & 31);
                    bf16x8 v = *reinterpret_cast<const bf16x8*>(smem + row * 512 + slot * 16);
                    *reinterpret_cast<bf16x8*>(
                        qk + (mbase + row) * 1024 + colbase + h2 * 128 + sl * 8) = v;
                }
            }
        } else {
            // v: LDS transposed [256 e][256 tok] bf16, slot ^= e&31 -> vT[win][e2][tok]
            #pragma unroll
            for (int ct = 0; ct < 4; ++ct) {
                float b = bias[colg0 + 16 * ct];
                int e = 64 * wn + 16 * ct + lrow;
                #pragma unroll
                for (int rt = 0; rt < 8; ++rt)
                    #pragma unroll
                    for (int r = 0; r < 4; ++r) {
                        int tok = 128 * wm + 16 * rt + 4 * hi + r;
                        *reinterpret_cast<__bf16*>(
                            smem + e * 512 + ((tok * 2) ^ ((e & 31) << 4))) =
                            (__bf16)(acc[rt][ct][r] + b);
                    }
            }
            LGKM0();
            __builtin_amdgcn_s_barrier();
            #pragma unroll
            for (int i = 0; i < 8; ++i) {
                int e = 32 * w + 4 * i + quad;
                #pragma unroll
                for (int h2 = 0; h2 < 2; ++h2) {
                    int slot = (16 * h2 + sl) ^ (e & 31);
                    bf16x8 v = *reinterpret_cast<const bf16x8*>(smem + e * 512 + slot * 16);
                    *reinterpret_cast<bf16x8*>(
                        vT + (long)(2 * midx + h2) * 65536 +
                        (colbase - 1024 + e) * 128 + sl * 8) = v;
                }
            }
        }
    } else {
        // fp32 out: two 128-row halves through LDS [128][256] f32, slot ^= row&63
        float* outp = (float*)Cq;
        float bb[4];
        #pragma unroll
        for (int ct = 0; ct < 4; ++ct) bb[ct] = bias[colg0 + 16 * ct];
        #pragma unroll 1
        for (int half = 0; half < 2; ++half) {
            if (wm == half) {
                #pragma unroll
                for (int ct = 0; ct < 4; ++ct) {
                    int c4 = (64 * wn + 16 * ct + lrow) * 4;
                    #pragma unroll
                    for (int rt = 0; rt < 8; ++rt)
                        #pragma unroll
                        for (int r = 0; r < 4; ++r) {
                            int row = 16 * rt + 4 * hi + r;
                            *reinterpret_cast<float*>(
                                smem + row * 1024 + (c4 ^ ((row & 63) << 4))) =
                                acc[rt][ct][r] + bb[ct];
                        }
                }
            }
            LGKM0();
            __builtin_amdgcn_s_barrier();
            #pragma unroll
            for (int i = 0; i < 4; ++i) {
                int row = 16 * w + 4 * i + quad;
                #pragma unroll
                for (int h2 = 0; h2 < 4; ++h2) {
                    int slot = (16 * h2 + sl) ^ (row & 63);
                    f32x4 v = *reinterpret_cast<const f32x4*>(smem + row * 1024 + slot * 16);
                    *reinterpret_cast<f32x4*>(
                        outp + (mbase + 128 * half + row) * 512 + colbase + h2 * 64 + sl * 4) = v;
                }
            }
            __builtin_amdgcn_s_barrier();
        }
    }
}

// ---------------- K3: attention per (window, head), no barriers ----------------
// grid = 2048 (win*8 + h), block = 256 (4 waves; wave w owns q rows 32w..32w+31)
__global__ __launch_bounds__(256)
void swa_attn(const __bf16* __restrict__ qk,   // [32768][1024]  q cols 0-511 (scaled), k cols 512-1023
              const __bf16* __restrict__ vT,   // [256][8][64][128]
              __bf16* __restrict__ ctx)        // [32768][512]
{
    __shared__ __bf16 p_lds[4][32][136];

    const int bid = blockIdx.x;
    const int win = bid >> 3, h = bid & 7;
    const int tid = threadIdx.x;
    const int w = tid >> 6, lane = tid & 63;
    const int lrow = lane & 15, hi = lane >> 4;
    const long tokb = (long)win * 128;

    // q a-frags for this wave's 32 rows (2 row-frags x 2 k-slices)
    bf16x8 qa[2][2];
    #pragma unroll
    for (int rt = 0; rt < 2; ++rt)
        #pragma unroll
        for (int ks = 0; ks < 2; ++ks)
            qa[rt][ks] = *reinterpret_cast<const bf16x8*>(
                qk + (tokb + 32 * w + 16 * rt + lrow) * 1024 + h * 64 + ks * 32 + hi * 8);

    // scores s[2][8]: 32 q-rows x 128 k-tokens
    f32x4 s[2][8];
    #pragma unroll
    for (int rt = 0; rt < 2; ++rt)
        #pragma unroll
        for (int ct = 0; ct < 8; ++ct) s[rt][ct] = (f32x4){0.f, 0.f, 0.f, 0.f};
    #pragma unroll
    for (int ks = 0; ks < 2; ++ks) {
        #pragma unroll
        for (int ct = 0; ct < 8; ++ct) {
            bf16x8 kb = *reinterpret_cast<const bf16x8*>(
                qk + (tokb + 16 * ct + lrow) * 1024 + 512 + h * 64 + ks * 32 + hi * 8);
            s[0][ct] = MFMA16(qa[0][ks], kb, s[0][ct]);
            s[1][ct] = MFMA16(qa[1][ks], kb, s[1][ct]);
        }
    }

    // softmax per row (row = 16rt + 4hi + r, cols spread over lrow x ct)
    float inv[2][4];
    #pragma unroll
    for (int rt = 0; rt < 2; ++rt) {
        #pragma unroll
        for (int r = 0; r < 4; ++r) {
            float m = s[rt][0][r];
            #pragma unroll
            for (int ct = 1; ct < 8; ++ct) m = fmaxf(m, s[rt][ct][r]);
            m = fmaxf(m, __shfl_xor(m, 1));
            m = fmaxf(m, __shfl_xor(m, 2));
            m = fmaxf(m, __shfl_xor(m, 4));
            m = fmaxf(m, __shfl_xor(m, 8));
            float sum = 0.f;
            #pragma unroll
            for (int ct = 0; ct < 8; ++ct) {
                float e = __expf(s[rt][ct][r] - m);
                sum += e;
                p_lds[w][16 * rt + 4 * hi + r][16 * ct + lrow] = (__bf16)e;
            }
            sum += __shfl_xor(sum, 1);
            sum += __shfl_xor(sum, 2);
            sum += __shfl_xor(sum, 4);
            sum += __shfl_xor(sum, 8);
            inv[rt][r] = 1.f / sum;
        }
    }
    // no barrier: p_lds[w] is wave-private; compiler orders same-wave LDS RAW

    // PV: o[2][4] = P @ V  (b-frag from vT: contiguous tok reads)
    f32x4 o[2][4];
    #pragma unroll
    for (int rt = 0; rt < 2; ++rt)
        #pragma unroll
        for (int ct = 0; ct < 4; ++ct) o[rt][ct] = (f32x4){0.f, 0.f, 0.f, 0.f};
    const __bf16* vb = vT + ((long)win * 8 + h) * 64 * 128;
    #pragma unroll
    for (int kt = 0; kt < 4; ++kt) {
        bf16x8 pa0 = *reinterpret_cast<const bf16x8*>(&p_lds[w][lrow][32 * kt + 8 * hi]);
        bf16x8 pa1 = *reinterpret_cast<const bf16x8*>(&p_lds[w][16 + lrow][32 * kt + 8 * hi]);
        #pragma unroll
        for (int ct = 0; ct < 4; ++ct) {
            bf16x8 vf = *reinterpret_cast<const bf16x8*>(
                vb + (16 * ct + lrow) * 128 + 32 * kt + 8 * hi);
            o[0][ct] = MFMA16(pa0, vf, o[0][ct]);
            o[1][ct] = MFMA16(pa1, vf, o[1][ct]);
        }
    }

    #pragma unroll
    for (int rt = 0; rt < 2; ++rt)
        #pragma unroll
        for (int ct = 0; ct < 4; ++ct)
            #pragma unroll
            for (int r = 0; r < 4; ++r) {
                long tok = tokb + 32 * w + 16 * rt + 4 * hi + r;
                ctx[tok * 512 + h * 64 + 16 * ct + lrow] =
                    (__bf16)(o[rt][ct][r] * inv[rt][r]);
            }
}

extern "C" void kernel_launch(void* const* d_in, const int* in_sizes, int n_in,
                              void* d_out, int out_size, void* d_ws, size_t ws_size,
                              hipStream_t stream)
{
    const float* x     = (const float*)d_in[0];
    const float* w_in  = (const float*)d_in[1];
    const float* b_in  = (const float*)d_in[2];
    const float* w_out = (const float*)d_in[3];
    const float* b_out = (const float*)d_in[4];

    // ws layout (bytes): [x_bf -> later ctx: 0, 33554432) [vT: 33554432, 67108864)
    //                    [w_in_bf: 67108864, +1572864) [w_out_bf: 68681728, +524288)
    // total 69,206,016 B. qk scratch (67.1 MB bf16) lives in d_out until K4.
    char* ws = (char*)d_ws;
    __bf16* x_bf     = (__bf16*)(ws);
    __bf16* ctx      = (__bf16*)(ws);                  // reuses x_bf after K2
    __bf16* vT       = (__bf16*)(ws + 33554432);
    __bf16* w_in_bf  = (__bf16*)(ws + 67108864);
    __bf16* w_out_bf = (__bf16*)(ws + 68681728);
    __bf16* qk       = (__bf16*)d_out;

    convert_k<<<2048, 256, 0, stream>>>(x, w_in, w_out, x_bf, w_in_bf, w_out_bf);
    gemm256<0, 6><<<768, 512, 0, stream>>>(x_bf, w_in_bf, b_in, (void*)qk, vT);
    swa_attn<<<2048, 256, 0, stream>>>(qk, vT, ctx);
    gemm256<1, 2><<<256, 512, 0, stream>>>(ctx, w_out_bf, b_out, d_out, nullptr);
}

// Round 7
// 154.676 us; speedup vs baseline: 1.1456x; 1.1456x over previous
//
#include <hip/hip_runtime.h>

// SWA non-overlapping window MHA, MI355X gfx950.
// K1 convert fp32->bf16 (x, w_in, w_out)
// K23 fused per-window QKV GEMM + attention -> ctx bf16 [M][512]
// K4 out-proj GEMM [32768x512x512] + bias -> fp32 d_out

typedef __bf16 bf16x8 __attribute__((ext_vector_type(8)));
typedef float  f32x4  __attribute__((ext_vector_type(4)));

#define MFMA16(a, b, c) __builtin_amdgcn_mfma_f32_16x16x32_bf16((a), (b), (c), 0, 0, 0)
#define VMCNT_(n) asm volatile("s_waitcnt vmcnt(" #n ")" ::: "memory")
#define VMCNT(n) VMCNT_(n)
#define LGKM0() asm volatile("s_waitcnt lgkmcnt(0)" ::: "memory")

__device__ __forceinline__ void gload_lds16(const __bf16* g, void* l) {
    __builtin_amdgcn_global_load_lds(
        (const __attribute__((address_space(1))) unsigned int*)g,
        (__attribute__((address_space(3))) unsigned int*)l, 16, 0, 0);
}

// ---------------- K1: fp32 -> bf16 conversion ----------------
__device__ __forceinline__ void cvt8(const float* __restrict__ s,
                                     __bf16* __restrict__ d, long i) {
    const float4* s4 = reinterpret_cast<const float4*>(s);
    float4 a = s4[2 * i], b = s4[2 * i + 1];
    bf16x8 v;
    v[0] = (__bf16)a.x; v[1] = (__bf16)a.y; v[2] = (__bf16)a.z; v[3] = (__bf16)a.w;
    v[4] = (__bf16)b.x; v[5] = (__bf16)b.y; v[6] = (__bf16)b.z; v[7] = (__bf16)b.w;
    *reinterpret_cast<bf16x8*>(d + 8 * i) = v;
}

__global__ void convert_k(const float* __restrict__ x,
                          const float* __restrict__ w_in,
                          const float* __restrict__ w_out,
                          __bf16* __restrict__ x_bf,
                          __bf16* __restrict__ w_in_bf,
                          __bf16* __restrict__ w_out_bf)
{
    long i0 = (long)blockIdx.x * blockDim.x + threadIdx.x;
    long stride = (long)gridDim.x * blockDim.x;
    for (long i = i0; i < 16777216 / 8; i += stride) cvt8(x, x_bf, i);
    for (long i = i0; i < 786432 / 8;   i += stride) cvt8(w_in, w_in_bf, i);
    for (long i = i0; i < 262144 / 8;   i += stride) cvt8(w_out, w_out_bf, i);
}

// ---------------- K23: fused per-window QKV + attention ----------------
// block = 1 window (256 blocks), 512 threads = 8 waves.
// Per head h: QKV GEMM M=128 x N=192 (q|k|v 64-col bands) x K=512,
//   A(x)/B(W) staged in ring-2 LDS (BK=64, 1 barrier + vmcnt(0) per tile),
//   wave grid 2 row x 4 col (rt=4, ct=3). Epilogue -> q,k (alias ring buf0), vT.
//   Attention = R0-verified code: wave w owns q rows 16w..16w+15.
// LDS: ring [0,81920) {A[128][128B], B[192][128B]} x2 ; q [0,18432) k [18432,36864)
//      vT [81920,99328) 64x272B ; p [99328,134144) 8x16x272B
__global__ __launch_bounds__(512, 2)
void swa_fused(const __bf16* __restrict__ x_bf,
               const __bf16* __restrict__ w_in,      // [1536][512] bf16
               const float* __restrict__ b_in,       // [1536]
               __bf16* __restrict__ ctx)             // [32768][512]
{
    __shared__ __align__(16) char smem[134144];
    char* const ring = smem;
    char* const q_l  = smem;
    char* const k_l  = smem + 18432;
    char* const vT_l = smem + 81920;
    char* const p_l  = smem + 99328;

    const int win = blockIdx.x;
    const long tokb = (long)win * 128;
    const int tid = threadIdx.x, w = tid >> 6, lane = tid & 63;
    const int lrow = lane & 15, hi = lane >> 4;
    const int rw = w >> 2, cw = w & 3;                // QKV wave grid 2x4
    const int l8 = lane >> 3;
    const int slotp = (lane & 7) ^ l8;                // pre-swizzled 16B k-slot

    const __bf16* Ax  = x_bf + (tokb + 8 * w + l8) * 512 + slotp * 8;
    const __bf16* Bx0 = w_in + (long)(8 * w + l8) * 512 + slotp * 8;

    auto stage = [&](int h, int t) {                  // 5 gload_lds16 / thread
        char* buf = ring + (t & 1) * 40960;
        const int ko = t * 64;
        const __bf16* Bx = Bx0 + (long)h * 64 * 512;
        gload_lds16(Ax + ko,                    buf + w * 1024);           // x rows 0..63
        gload_lds16(Ax + 64 * 512 + ko,         buf + 8192 + w * 1024);    // x rows 64..127
        gload_lds16(Bx + ko,                    buf + 16384 + w * 1024);   // W band q
        gload_lds16(Bx + (long)512 * 512 + ko,  buf + 24576 + w * 1024);   // W band k
        gload_lds16(Bx + (long)1024 * 512 + ko, buf + 32768 + w * 1024);   // W band v
    };

    stage(0, 0);

    #pragma unroll 1
    for (int h = 0; h < 8; ++h) {
        // ---- QKV K-loop: 8 tiles of BK=64, ring-2, 1 barrier/tile ----
        f32x4 acc[4][3];
        #pragma unroll
        for (int i = 0; i < 4; ++i)
            #pragma unroll
            for (int j = 0; j < 3; ++j) acc[i][j] = (f32x4){0.f, 0.f, 0.f, 0.f};

        #pragma unroll 1
        for (int t = 0; t < 8; ++t) {
            VMCNT(0);                                 // tile t landed (issued 1 tile ago)
            LGKM0();
            __builtin_amdgcn_s_barrier();             // all waves done reading buf (t-1)&1
            if (t < 7) stage(h, t + 1);
            const char* As = ring + (t & 1) * 40960;
            const char* Bs = As + 16384;
            #pragma unroll
            for (int kk = 0; kk < 2; ++kk) {
                const int ko = (kk * 64 + hi * 16) ^ ((lrow & 7) << 4);
                bf16x8 af[4], bfr[3];
                #pragma unroll
                for (int i = 0; i < 4; ++i)
                    af[i] = *reinterpret_cast<const bf16x8*>(
                        As + (64 * rw + 16 * i + lrow) * 128 + ko);
                #pragma unroll
                for (int j = 0; j < 3; ++j)
                    bfr[j] = *reinterpret_cast<const bf16x8*>(
                        Bs + (48 * cw + 16 * j + lrow) * 128 + ko);
                __builtin_amdgcn_s_setprio(1);
                #pragma unroll
                for (int i = 0; i < 4; ++i)
                    #pragma unroll
                    for (int j = 0; j < 3; ++j)
                        acc[i][j] = MFMA16(af[i], bfr[j], acc[i][j]);
                __builtin_amdgcn_s_setprio(0);
            }
        }
        LGKM0();
        __builtin_amdgcn_s_barrier();                 // ring dead; safe to write q,k,vT

        // ---- epilogue: acc -> q (scaled), k, vT in LDS ----
        #pragma unroll
        for (int j = 0; j < 3; ++j) {
            const int n = 48 * cw + 16 * j + lrow;    // col within [0,192)
            const int band = n >> 6, d = n & 63;
            const float bb = b_in[band * 512 + h * 64 + d];
            #pragma unroll
            for (int i = 0; i < 4; ++i)
                #pragma unroll
                for (int r = 0; r < 4; ++r) {
                    const int m = 64 * rw + 16 * i + 4 * hi + r;
                    const float v = acc[i][j][r] + bb;
                    if (band == 0)
                        *reinterpret_cast<__bf16*>(q_l + m * 144 + d * 2) = (__bf16)(v * 0.125f);
                    else if (band == 1)
                        *reinterpret_cast<__bf16*>(k_l + m * 144 + d * 2) = (__bf16)v;
                    else
                        *reinterpret_cast<__bf16*>(vT_l + d * 272 + m * 2) = (__bf16)v;
                }
        }
        LGKM0();
        __builtin_amdgcn_s_barrier();                 // q,k,vT visible to all waves

        // ---- scores: wave w owns q rows 16w..16w+15 (R0-verified layout) ----
        f32x4 s[8];
        #pragma unroll
        for (int ct = 0; ct < 8; ++ct) s[ct] = (f32x4){0.f, 0.f, 0.f, 0.f};
        #pragma unroll
        for (int kt = 0; kt < 2; ++kt) {
            bf16x8 qa = *reinterpret_cast<const bf16x8*>(
                q_l + (16 * w + lrow) * 144 + kt * 64 + hi * 16);
            #pragma unroll
            for (int ct = 0; ct < 8; ++ct) {
                bf16x8 kb = *reinterpret_cast<const bf16x8*>(
                    k_l + (16 * ct + lrow) * 144 + kt * 64 + hi * 16);
                s[ct] = MFMA16(qa, kb, s[ct]);
            }
        }
        LGKM0();
        __builtin_amdgcn_s_barrier();                 // q,k reads done -> buf0 free
        if (h < 7) stage(h + 1, 0);                   // prefetch next head's tile 0

        // ---- softmax (row m = 4*hi + r within wave; 16-lane reduce) ----
        float inv[4];
        #pragma unroll
        for (int r = 0; r < 4; ++r) {
            float mx = s[0][r];
            #pragma unroll
            for (int ct = 1; ct < 8; ++ct) mx = fmaxf(mx, s[ct][r]);
            mx = fmaxf(mx, __shfl_xor(mx, 1));
            mx = fmaxf(mx, __shfl_xor(mx, 2));
            mx = fmaxf(mx, __shfl_xor(mx, 4));
            mx = fmaxf(mx, __shfl_xor(mx, 8));
            float sum = 0.f;
            #pragma unroll
            for (int ct = 0; ct < 8; ++ct) {
                float e = __expf(s[ct][r] - mx);
                sum += e;
                *reinterpret_cast<__bf16*>(
                    p_l + w * 4352 + (4 * hi + r) * 272 + (16 * ct + lrow) * 2) = (__bf16)e;
            }
            sum += __shfl_xor(sum, 1);
            sum += __shfl_xor(sum, 2);
            sum += __shfl_xor(sum, 4);
            sum += __shfl_xor(sum, 8);
            inv[r] = 1.f / sum;
        }
        // p_l[w] wave-private: same-wave ds_write->ds_read ordered by compiler

        // ---- PV: o = P @ V ----
        f32x4 o[4];
        #pragma unroll
        for (int ct = 0; ct < 4; ++ct) o[ct] = (f32x4){0.f, 0.f, 0.f, 0.f};
        #pragma unroll
        for (int kt = 0; kt < 4; ++kt) {
            bf16x8 pa = *reinterpret_cast<const bf16x8*>(
                p_l + w * 4352 + lrow * 272 + kt * 64 + hi * 16);
            #pragma unroll
            for (int ct = 0; ct < 4; ++ct) {
                bf16x8 vf = *reinterpret_cast<const bf16x8*>(
                    vT_l + (16 * ct + lrow) * 272 + kt * 64 + hi * 16);
                o[ct] = MFMA16(pa, vf, o[ct]);
            }
        }
        #pragma unroll
        for (int ct = 0; ct < 4; ++ct)
            #pragma unroll
            for (int r = 0; r < 4; ++r) {
                long tok = tokb + 16 * w + 4 * hi + r;
                ctx[tok * 512 + h * 64 + 16 * ct + lrow] = (__bf16)(o[ct][r] * inv[r]);
            }
        // next head's t=0 barrier (after vmcnt/lgkm) provides the closing sync
    }
}

// ---------------- K4: out-proj 256x256xBK64, 4 phases/tile, direct epilogue ----------------
__global__ __launch_bounds__(512, 2)
void gemm_out(const __bf16* __restrict__ A,          // ctx [32768][512]
              const __bf16* __restrict__ Bw,         // w_out [512][512]
              const float* __restrict__ bias,
              float* __restrict__ out)
{
    __shared__ __align__(16) char smem[131072];

    const int nwg = gridDim.x;                        // 256
    const int chunk = nwg >> 3;
    const int bid = blockIdx.x;
    const int wg = (bid & 7) * chunk + (bid >> 3);
    const int nidx = wg % 2;
    const int midx = wg / 2;
    const long mbase = (long)midx * 256;
    const int colbase = nidx * 256;

    const int tid = threadIdx.x;
    const int w = tid >> 6, lane = tid & 63;
    const int lrow = lane & 15, hi = lane >> 4;
    const int wm = w >> 2, wn = w & 3;

    const int l8 = lane >> 3;
    const int slotp = (lane & 7) ^ l8;
    const __bf16* stA = A  + (mbase + 8 * w + l8) * 512 + slotp * 8;
    const __bf16* stB = Bw + ((long)colbase + 8 * w + l8) * 512 + slotp * 8;
    const int ldsw = w * 1024;

    auto stage8 = [&](int tt) {
        char* As = smem + (tt & 1) * 32768;
        char* Bs = smem + 65536 + (tt & 1) * 32768;
        const int ko = tt * 64;
        gload_lds16(stA + ko,             As + ldsw);
        gload_lds16(stA + 64 * 512 + ko,  As + 8192 + ldsw);
        gload_lds16(stA + 128 * 512 + ko, As + 16384 + ldsw);
        gload_lds16(stA + 192 * 512 + ko, As + 24576 + ldsw);
        gload_lds16(stB + ko,             Bs + ldsw);
        gload_lds16(stB + 64 * 512 + ko,  Bs + 8192 + ldsw);
        gload_lds16(stB + 128 * 512 + ko, Bs + 16384 + ldsw);
        gload_lds16(stB + 192 * 512 + ko, Bs + 24576 + ldsw);
    };

    f32x4 acc[8][4];
    #pragma unroll
    for (int rt = 0; rt < 8; ++rt)
        #pragma unroll
        for (int ct = 0; ct < 4; ++ct) acc[rt][ct] = (f32x4){0.f, 0.f, 0.f, 0.f};

    bf16x8 af[4], bfr[4];
#define PHASE(T, KK, RT0, LB)                                                     \
    {                                                                             \
        const char* As = smem + ((T) & 1) * 32768;                                \
        const char* Bs = smem + 65536 + ((T) & 1) * 32768;                        \
        const int ko = ((KK) * 64 + hi * 16) ^ ((lrow & 7) << 4);                 \
        if (LB) {                                                                 \
            _Pragma("unroll")                                                     \
            for (int ct = 0; ct < 4; ++ct)                                        \
                bfr[ct] = *reinterpret_cast<const bf16x8*>(                       \
                    Bs + (64 * wn + 16 * ct + lrow) * 128 + ko);                  \
        }                                                                         \
        _Pragma("unroll")                                                         \
        for (int i = 0; i < 4; ++i)                                               \
            af[i] = *reinterpret_cast<const bf16x8*>(                             \
                As + (128 * wm + 16 * ((RT0) + i) + lrow) * 128 + ko);            \
        __builtin_amdgcn_s_setprio(1);                                            \
        _Pragma("unroll")                                                         \
        for (int i = 0; i < 4; ++i)                                               \
            _Pragma("unroll")                                                     \
            for (int ct = 0; ct < 4; ++ct)                                        \
                acc[(RT0) + i][ct] = MFMA16(af[i], bfr[ct], acc[(RT0) + i][ct]);  \
        __builtin_amdgcn_s_setprio(0);                                            \
    }

    stage8(0); stage8(1);
    VMCNT(8);
    __builtin_amdgcn_s_barrier();

    #pragma unroll 1
    for (int t = 0; t < 8; ++t) {
        if (t) {
            VMCNT(0);
            __builtin_amdgcn_s_barrier();
            if (t < 7) stage8(t + 1);
        }
        PHASE(t, 0, 0, 1);
        __builtin_amdgcn_s_barrier();
        PHASE(t, 0, 4, 0);
        __builtin_amdgcn_s_barrier();
        PHASE(t, 1, 0, 1);
        __builtin_amdgcn_s_barrier();
        PHASE(t, 1, 4, 0);
    }
#undef PHASE

    // direct fp32 epilogue: 16 lanes store 16 consecutive fp32 = full 64B sectors
    #pragma unroll
    for (int ct = 0; ct < 4; ++ct) {
        int colg = colbase + 64 * wn + 16 * ct + lrow;
        float b = bias[colg];
        #pragma unroll
        for (int rt = 0; rt < 8; ++rt) {
            long row = mbase + 128 * wm + 16 * rt + 4 * hi;
            #pragma unroll
            for (int r = 0; r < 4; ++r)
                out[(row + r) * 512 + colg] = acc[rt][ct][r] + b;
        }
    }
}

extern "C" void kernel_launch(void* const* d_in, const int* in_sizes, int n_in,
                              void* d_out, int out_size, void* d_ws, size_t ws_size,
                              hipStream_t stream)
{
    const float* x     = (const float*)d_in[0];
    const float* w_in  = (const float*)d_in[1];
    const float* b_in  = (const float*)d_in[2];
    const float* w_out = (const float*)d_in[3];
    const float* b_out = (const float*)d_in[4];

    // ws: [x_bf: 0, 33554432) [ctx: 33554432, 67108864)
    //     [w_in_bf: 67108864, +1572864) [w_out_bf: 68681728, +524288) = 69,206,016 B
    char* ws = (char*)d_ws;
    __bf16* x_bf     = (__bf16*)(ws);
    __bf16* ctx      = (__bf16*)(ws + 33554432);
    __bf16* w_in_bf  = (__bf16*)(ws + 67108864);
    __bf16* w_out_bf = (__bf16*)(ws + 68681728);

    convert_k<<<2048, 256, 0, stream>>>(x, w_in, w_out, x_bf, w_in_bf, w_out_bf);
    swa_fused<<<256, 512, 0, stream>>>(x_bf, w_in_bf, b_in, ctx);
    gemm_out<<<256, 512, 0, stream>>>(ctx, w_out_bf, b_out, (float*)d_out);
}